// Round 12
// baseline (373.577 us; speedup 1.0000x reference)
//
#include <hip/hip_runtime.h>
#include <hip/hip_bf16.h>

#define NQ     300
#define NH     8
#define HID    256
#define NLVL   4
#define NCELL  49
#define TOTAL  21760

typedef unsigned short ushort_t;
typedef __attribute__((ext_vector_type(8))) short short8;
typedef __attribute__((ext_vector_type(4))) float floatx4;
typedef __attribute__((ext_vector_type(2))) float floatx2;
typedef __attribute__((ext_vector_type(4))) unsigned int uintx4;

__device__ __forceinline__ float bfbits2f(ushort_t u) {
    union { unsigned int i; float f; } x;
    x.i = ((unsigned int)u) << 16;
    return x.f;
}
__device__ __forceinline__ ushort_t f2bfbits(float v) {
    __hip_bfloat16 h = __float2bfloat16(v);
    return *(ushort_t*)&h;
}
__device__ __forceinline__ unsigned int pack2bf(float a, float b) {
    return (unsigned int)f2bfbits(a) | ((unsigned int)f2bfbits(b) << 16);
}
__device__ __forceinline__ void split_bf(float v, ushort_t& hi, ushort_t& lo) {
    __hip_bfloat16 h = __float2bfloat16(v);
    hi = *(ushort_t*)&h;
    float hv = __bfloat162float(h);
    __hip_bfloat16 l = __float2bfloat16(v - hv);
    lo = *(ushort_t*)&l;
}

// packed f32 FMA: 2 FMAs per issue slot (CDNA v_pk_fma_f32)
__device__ __forceinline__ floatx2 pk_fma(floatx2 a, floatx2 b, floatx2 c) {
    floatx2 d;
    asm("v_pk_fma_f32 %0, %1, %2, %3" : "=v"(d) : "v"(a), "v"(b), "v"(c));
    return d;
}
// uint (2 packed bf16) -> {lo, hi} as exact f32 pair
__device__ __forceinline__ floatx2 unpack2(unsigned int u) {
    union { unsigned int i; float f; } lo, hi;
    lo.i = u << 16;
    hi.i = u & 0xffff0000u;
    return (floatx2){lo.f, hi.f};
}
// explicit async 16B load (k_roip1): issued in program order, untracked by the
// compiler's waitcnt insertion. Valid only after s_waitcnt vmcnt(0)+sched_barrier.
__device__ __forceinline__ uintx4 ld_async_b128(const ushort_t* p) {
    uintx4 d;
    asm volatile("global_load_dwordx4 %0, %1, off" : "=v"(d) : "v"(p));
    return d;
}

// ---------------------------------------------------------------------------
// ROI helpers — bf16 memory (validated rounds 9-10)
// ---------------------------------------------------------------------------
struct Box {
    float sx, sy, bw, bh, Wf;
    int W;
    const ushort_t* memb;
};

__device__ __forceinline__ void load_box(const float* __restrict__ refr,
                                         const ushort_t* __restrict__ mem16,
                                         int r, int lvl, int ch, Box& bx) {
    const int lvl_hw[4] = {128, 64, 32, 16};
    const int lvl_s[4]  = {0, 16384, 20480, 21504};
    const int b = r / NQ;
    bx.W  = lvl_hw[lvl];
    bx.Wf = (float)bx.W;
    const float* rp = refr + ((size_t)r * NLVL + lvl) * 6;
    float cx = rp[0], cy = rp[1];
    float dl = rp[2], dt = rp[3], dr = rp[4], db = rp[5];
    float x1 = fminf(fmaxf(cx - dl, 0.f), 1.f) * bx.Wf;
    float y1 = fminf(fmaxf(cy - dt, 0.f), 1.f) * bx.Wf;
    float x2 = fminf(fmaxf(cx + dr, 0.f), 1.f) * bx.Wf;
    float y2 = fminf(fmaxf(cy + db, 0.f), 1.f) * bx.Wf;
    bx.sx = x1 - 0.5f;
    bx.sy = y1 - 0.5f;
    bx.bw = (x2 - x1) * (1.f / 7.f);
    bx.bh = (y2 - y1) * (1.f / 7.f);
    bx.memb = mem16 + ((size_t)b * TOTAL + lvl_s[lvl]) * HID + ch;
}

// ---------------------------------------------------------------------------
// Merged prep: esplit(tgt) + 5x tsplit + memory->bf16  (one launch)
// ---------------------------------------------------------------------------
__device__ __forceinline__ void tsplit_body(const float* __restrict__ W,
                                            ushort_t* __restrict__ TH,
                                            ushort_t* __restrict__ TL,
                                            int K, int N, int kb, int nb,
                                            int perm, int tid, float (*sm)[65]) {
    for (int e = tid; e < 64 * 64; e += 256) {
        int kk = e >> 6, nn = e & 63;
        int kp = kb + kk;
        int ks = perm ? ((kp & 63) * 49 + (kp >> 6)) : kp;
        sm[kk][nn] = W[(size_t)ks * N + nb + nn];
    }
    __syncthreads();
    for (int e = tid; e < 64 * 64; e += 256) {
        int nn = e >> 6, kk = e & 63;
        ushort_t h, l;
        split_bf(sm[kk][nn], h, l);
        size_t o = (size_t)(nb + nn) * K + kb + kk;
        TH[o] = h; TL[o] = l;
    }
}

__global__ __launch_bounds__(256) void k_prep(
    const float* __restrict__ tgt, ushort_t* __restrict__ tgtH, ushort_t* __restrict__ tgtL,
    const float* __restrict__ a1w, ushort_t* __restrict__ a1wTH, ushort_t* __restrict__ a1wTL,
    const float* __restrict__ w1, ushort_t* __restrict__ w1TH, ushort_t* __restrict__ w1TL,
    const float* __restrict__ w2, ushort_t* __restrict__ w2TH, ushort_t* __restrict__ w2TL,
    const float* __restrict__ w3, ushort_t* __restrict__ w3TH, ushort_t* __restrict__ w3TL,
    const float* __restrict__ p1w, ushort_t* __restrict__ p1wTH, ushort_t* __restrict__ p1wTL,
    const float* __restrict__ memory, ushort_t* __restrict__ mem16) {
    __shared__ float sm[64][65];
    const int tid = threadIdx.x;
    int b = blockIdx.x;
    if (b < 600) {                       // esplit on tgt (600*256 elems)
        int i = b * 256 + tid;
        ushort_t h, l;
        split_bf(tgt[i], h, l);
        tgtH[i] = h; tgtL[i] = l;
    } else if (b < 728) {                // a1w: K=256 x N=2048
        b -= 600;
        tsplit_body(a1w, a1wTH, a1wTL, 256, 2048, (b % 4) * 64, (b / 4) * 64, 0, tid, sm);
    } else if (b < 924) {                // w1: K=3136 x N=256, PERM
        b -= 728;
        tsplit_body(w1, w1TH, w1TL, 3136, 256, (b % 49) * 64, (b / 49) * 64, 1, tid, sm);
    } else if (b < 956) {                // w2: K=256 x N=512
        b -= 924;
        tsplit_body(w2, w2TH, w2TL, 256, 512, (b % 4) * 64, (b / 4) * 64, 0, tid, sm);
    } else if (b < 1020) {               // w3: K=512 x N=512
        b -= 956;
        tsplit_body(w3, w3TH, w3TL, 512, 512, (b % 8) * 64, (b / 8) * 64, 0, tid, sm);
    } else if (b < 1024) {               // p1w: K=256 x N=64
        b -= 1020;
        tsplit_body(p1w, p1wTH, p1wTL, 256, 64, b * 64, 0, 0, tid, sm);
    } else {                             // memory -> bf16 (10880 blocks)
        b -= 1024;
        size_t i = (size_t)b * 256 + tid;   // float4 index
        float4 v = ((const float4*)memory)[i];
        ushort4 o;
        o.x = f2bfbits(v.x); o.y = f2bfbits(v.y);
        o.z = f2bfbits(v.z); o.w = f2bfbits(v.w);
        ((ushort4*)mem16)[i] = o;
    }
}

// ---------------------------------------------------------------------------
// w1 split-K GEMM with 64x128 tile (round 21).
// ---------------------------------------------------------------------------
__global__ __launch_bounds__(256) void k_w1(
    const ushort_t* __restrict__ AH, const ushort_t* __restrict__ AL,
    const ushort_t* __restrict__ WH, const ushort_t* __restrict__ WL,
    float* __restrict__ Cf, int M, int N, int K, int kchunk) {
    __shared__ ushort_t As[2][64][40];
    __shared__ ushort_t Ws[2][128][40];

    const int tid = threadIdx.x;
    const int m0 = blockIdx.x * 64, n0 = blockIdx.y * 128;
    const int wv = tid >> 6, ln = tid & 63;
    const int arow_s = tid >> 2, akc = tid & 3;        // A staging
    const int wrow_s = tid >> 1, wko = (tid & 1) * 16; // W staging (2 uint4 each)
    const int gm = min(m0 + arow_s, M - 1);
    const int gn = n0 + wrow_s;
    const int arow = wv * 16 + (ln & 15);
    const int koff = (ln >> 4) * 8;

    const int kb = blockIdx.z * kchunk;
    const int ke = min(K, kb + kchunk);

    floatx4 acc[8];
#pragma unroll
    for (int t = 0; t < 8; ++t) acc[t] = (floatx4){0.f, 0.f, 0.f, 0.f};

    for (int k0 = kb; k0 < ke; k0 += 32) {
        *(uint4*)&As[0][arow_s][akc * 8] = *(const uint4*)(AH + (size_t)gm * K + k0 + akc * 8);
        *(uint4*)&As[1][arow_s][akc * 8] = *(const uint4*)(AL + (size_t)gm * K + k0 + akc * 8);
        *(uint4*)&Ws[0][wrow_s][wko]     = *(const uint4*)(WH + (size_t)gn * K + k0 + wko);
        *(uint4*)&Ws[0][wrow_s][wko + 8] = *(const uint4*)(WH + (size_t)gn * K + k0 + wko + 8);
        *(uint4*)&Ws[1][wrow_s][wko]     = *(const uint4*)(WL + (size_t)gn * K + k0 + wko);
        *(uint4*)&Ws[1][wrow_s][wko + 8] = *(const uint4*)(WL + (size_t)gn * K + k0 + wko + 8);
        __syncthreads();

        short8 aH = *(short8*)&As[0][arow][koff];
        short8 aL = *(short8*)&As[1][arow][koff];
#pragma unroll
        for (int t = 0; t < 8; ++t) {
            short8 wH = *(short8*)&Ws[0][t * 16 + (ln & 15)][koff];
            short8 wL = *(short8*)&Ws[1][t * 16 + (ln & 15)][koff];
            acc[t] = __builtin_amdgcn_mfma_f32_16x16x32_bf16(aH, wH, acc[t], 0, 0, 0);
            acc[t] = __builtin_amdgcn_mfma_f32_16x16x32_bf16(aH, wL, acc[t], 0, 0, 0);
            acc[t] = __builtin_amdgcn_mfma_f32_16x16x32_bf16(aL, wH, acc[t], 0, 0, 0);
        }
        __syncthreads();
    }

    float* Cpart = Cf + (size_t)blockIdx.z * M * N;
#pragma unroll
    for (int t = 0; t < 8; ++t) {
        const int n = n0 + t * 16 + (ln & 15);
#pragma unroll
        for (int reg = 0; reg < 4; ++reg) {
            const int m = m0 + wv * 16 + (ln >> 4) * 4 + reg;
            if (m < M) Cpart[(size_t)m * N + n] = acc[t][reg];
        }
    }
}

// ---------------------------------------------------------------------------
// W-resident GEMM for small-W shapes (gate/w2/w3) — validated round 6.
// ---------------------------------------------------------------------------
template <int EPI, int AX, int KK, int NT>
__global__ __launch_bounds__(256) void k_wres(
    const ushort_t* __restrict__ AH, const ushort_t* __restrict__ AL,
    const ushort_t* __restrict__ WH, const ushort_t* __restrict__ WL,
    const float* __restrict__ bias, float* __restrict__ Cf,
    ushort_t* __restrict__ CH, ushort_t* __restrict__ CL,
    int M, int N, int nbm) {
    constexpr int KC = KK / 8;                 // 16B chunks per W row
    __shared__ ushort_t Wls[2 * NT * KK];      // 64 KB for both configs

    const int tid = threadIdx.x;
    const int m0 = (blockIdx.x % nbm) * 128;
    const int n0 = (blockIdx.x / nbm) * NT;

    // stage W rows n0..n0+NT-1 (full K), hi then lo, XOR-swizzled chunks
    {
        const uint4* sH = (const uint4*)(WH + (size_t)n0 * KK);
        const uint4* sL = (const uint4*)(WL + (size_t)n0 * KK);
        uint4* d = (uint4*)Wls;
        for (int i = tid; i < NT * KC; i += 256) {
            const int nn = i / KC, kk = i % KC;
            const int sw = nn * KC + (kk ^ (nn & 7));
            d[sw] = sH[i];
            d[NT * KC + sw] = sL[i];
        }
    }
    __syncthreads();

    const int wv = tid >> 6, ln = tid & 63;
    const int koff = (ln >> 4) * 8, nidx = ln & 15;
    const size_t a0 = (size_t)min(m0 + wv * 16 + (ln & 15), M - 1) * KK;
    const size_t a1 = (size_t)min(m0 + 64 + wv * 16 + (ln & 15), M - 1) * KK;

    floatx4 acc[2][NT / 16];
#pragma unroll
    for (int s = 0; s < 2; ++s)
#pragma unroll
        for (int t = 0; t < NT / 16; ++t) acc[s][t] = (floatx4){0.f, 0.f, 0.f, 0.f};

    for (int k0 = 0; k0 < KK; k0 += 32) {
        short8 a0H = *(const short8*)(AH + a0 + k0 + koff);
        short8 a1H = *(const short8*)(AH + a1 + k0 + koff);
        short8 a0L = a0H, a1L = a1H;
        if constexpr (!AX) {
            a0L = *(const short8*)(AL + a0 + k0 + koff);
            a1L = *(const short8*)(AL + a1 + k0 + koff);
        }
        const int kc = (k0 + koff) >> 3;
#pragma unroll
        for (int t = 0; t < NT / 16; ++t) {
            const int wrow = t * 16 + nidx;
            const int swr = wrow * KC + (kc ^ (wrow & 7));
            short8 wHf = *(const short8*)((const uint4*)Wls + swr);
            short8 wLf = *(const short8*)((const uint4*)Wls + NT * KC + swr);
            acc[0][t] = __builtin_amdgcn_mfma_f32_16x16x32_bf16(a0H, wHf, acc[0][t], 0, 0, 0);
            acc[0][t] = __builtin_amdgcn_mfma_f32_16x16x32_bf16(a0H, wLf, acc[0][t], 0, 0, 0);
            if constexpr (!AX)
                acc[0][t] = __builtin_amdgcn_mfma_f32_16x16x32_bf16(a0L, wHf, acc[0][t], 0, 0, 0);
            acc[1][t] = __builtin_amdgcn_mfma_f32_16x16x32_bf16(a1H, wHf, acc[1][t], 0, 0, 0);
            acc[1][t] = __builtin_amdgcn_mfma_f32_16x16x32_bf16(a1H, wLf, acc[1][t], 0, 0, 0);
            if constexpr (!AX)
                acc[1][t] = __builtin_amdgcn_mfma_f32_16x16x32_bf16(a1L, wHf, acc[1][t], 0, 0, 0);
        }
    }

#pragma unroll
    for (int s = 0; s < 2; ++s)
#pragma unroll
        for (int t = 0; t < NT / 16; ++t) {
            const int n = n0 + t * 16 + nidx;
            const float bv = bias[n];
#pragma unroll
            for (int reg = 0; reg < 4; ++reg) {
                const int m = m0 + s * 64 + wv * 16 + (ln >> 4) * 4 + reg;
                if (m < M) {
                    float v = acc[s][t][reg] + bv;
                    if constexpr (EPI == 0) {
                        v = fmaxf(v, 0.f);
                        ushort_t h, l;
                        split_bf(v, h, l);
                        CH[(size_t)m * N + n] = h;
                        CL[(size_t)m * N + n] = l;
                    } else if constexpr (EPI == 1) {
                        Cf[(size_t)m * N + n] = fmaxf(v, 0.f);
                    } else {
                        Cf[(size_t)m * N + n] = 1.f / (1.f + expf(-v));
                    }
                }
            }
        }
}

// ---------------------------------------------------------------------------
// Split-K reduction for h1: sum 7 partials + bias, relu, hi/lo split.
// ---------------------------------------------------------------------------
__global__ __launch_bounds__(256) void k_h1red(
    const float* __restrict__ h1p, const float* __restrict__ b1,
    ushort_t* __restrict__ h1H, ushort_t* __restrict__ h1L) {
    const int idx = blockIdx.x * 256 + threadIdx.x;    // float4 index
    const int n = (idx * 4) & 255;
    float4 s = ((const float4*)h1p)[idx];
#pragma unroll
    for (int z = 1; z < 7; ++z) {
        float4 t = ((const float4*)(h1p + (size_t)z * 2400 * 256))[idx];
        s.x += t.x; s.y += t.y; s.z += t.z; s.w += t.w;
    }
    float4 bv = *(const float4*)(b1 + n);
    s.x = fmaxf(s.x + bv.x, 0.f);
    s.y = fmaxf(s.y + bv.y, 0.f);
    s.z = fmaxf(s.z + bv.z, 0.f);
    s.w = fmaxf(s.w + bv.w, 0.f);
    ushort4 H, L;
    split_bf(s.x, H.x, L.x);
    split_bf(s.y, H.y, L.y);
    split_bf(s.z, H.z, L.z);
    split_bf(s.w, H.w, L.w);
    ((ushort4*)h1H)[idx] = H;
    ((ushort4*)h1L)[idx] = L;
}

// ---------------------------------------------------------------------------
// pts = tanh(h3 @ w4 + b4): (2400 x 512) @ (512 x 16). (round 19)
// ---------------------------------------------------------------------------
__global__ __launch_bounds__(256) void k_pts(
    const float* __restrict__ h3, const float* __restrict__ w4,
    const float* __restrict__ b4, float* __restrict__ pts) {
    __shared__ float w4s[512 * 16];
    const int tid = threadIdx.x;
    for (int i = tid; i < 512 * 16 / 4; i += 256)
        ((float4*)w4s)[i] = ((const float4*)w4)[i];
    __syncthreads();

    const int row = blockIdx.x * 4 + (tid >> 6);   // 4 h3-rows per block
    const int col = (tid >> 2) & 15;
    const int ks  = tid & 3;
    const float* hrow = h3 + (size_t)row * 512 + ks * 128;
    float part = 0.f;
    for (int k = 0; k < 128; ++k)
        part += hrow[k] * w4s[(ks * 128 + k) * 16 + col];
    part += __shfl_down(part, 2);
    part += __shfl_down(part, 1);
    if (ks == 0) pts[row * 16 + col] = tanhf(part + b4[col]);
}

// ---------------------------------------------------------------------------
// Round 22: k_roi + p1 fused. Per (r,lvl) block: gather 49 roi cells
// (unchanged math), write roi to global (k_fuse needs it) AND to a 32KB
// XOR-swizzled LDS tile (same packed bf16 bits); one barrier; then the
// p1 GEMM (64x64x256) with A frags from LDS and W (p1wT, 64KB, L2-hot)
// from global. Same k-ascending wH-then-wL MFMA order as k_wres<0,1,256,64>
// -> bit-identical pHb/pLb. Eliminates the p1 dispatch + its 60MB roi
// re-read; MFMA lands on k_roi's idle matrix pipe.
// ---------------------------------------------------------------------------
__global__ __launch_bounds__(256) void k_roip1(
    const ushort_t* __restrict__ mem16, const float* __restrict__ refr,
    ushort_t* __restrict__ roi,
    const ushort_t* __restrict__ WH, const ushort_t* __restrict__ WL,
    const float* __restrict__ bias,
    ushort_t* __restrict__ CH, ushort_t* __restrict__ CL) {
    __shared__ uint4 As4[64 * 32];         // 32 KB roi tile, chunk^(row&7) swizzle

    const int tid  = threadIdx.x;
    const int wave = tid >> 6, lane = tid & 63;
    const int half = lane >> 5;            // which cell of the pair
    const int chv  = (lane & 31) * 8;      // 8 channels per lane
    const int lvl  = blockIdx.x & 3;       // interleaved: balance slow lvl-0
    const int r    = blockIdx.x >> 2;
    const int i2   = r * 4 + lvl;

    Box bx;
    load_box(refr, mem16, r, lvl, chv, bx);
    const int rowstride = bx.W * HID;

    ushort_t* rbase = roi + (size_t)i2 * NCELL * HID + chv;

    // ---- gather phase: 25 cell-pairs, 4 waves ----
    for (int k = wave; k < 25; k += 4) {
        const int cell = 2 * k + half;
        const int c = (cell < NCELL) ? cell : (NCELL - 1);
        const int ph = c / 7, pw = c % 7;

        uintx4 ld[16];
        float  w[16];
#pragma unroll
        for (int sub = 0; sub < 4; ++sub) {
            const float tys = (float)ph + ((sub >> 1) + 0.5f) * 0.5f;
            const float txs = (float)pw + ((sub & 1) + 0.5f) * 0.5f;
            const float yy = bx.sy + bx.bh * tys;
            const float xx = bx.sx + bx.bw * txs;
            const float vm = (yy >= -1.f && yy <= bx.Wf && xx <= bx.Wf && xx >= -1.f)
                             ? 0.25f : 0.f;
            const float yc  = fminf(fmaxf(yy, 0.f), bx.Wf - 1.f);
            const float xc  = fminf(fmaxf(xx, 0.f), bx.Wf - 1.f);
            const float y0f = fminf(floorf(yc), bx.Wf - 2.f);
            const float x0f = fminf(floorf(xc), bx.Wf - 2.f);
            const float ly = yc - y0f, lx = xc - x0f;
            const int   y0 = (int)y0f, x0 = (int)x0f;
            const ushort_t* p00 = bx.memb + (y0 * bx.W + x0) * HID;
            ld[sub * 4 + 0] = ld_async_b128(p00);
            ld[sub * 4 + 1] = ld_async_b128(p00 + HID);
            ld[sub * 4 + 2] = ld_async_b128(p00 + rowstride);
            ld[sub * 4 + 3] = ld_async_b128(p00 + rowstride + HID);
            const float omy = 1.f - ly, omx = 1.f - lx;
            w[sub * 4 + 0] = vm * omy * omx;
            w[sub * 4 + 1] = vm * omy * lx;
            w[sub * 4 + 2] = vm * ly  * omx;
            w[sub * 4 + 3] = vm * ly  * lx;
        }

        asm volatile("s_waitcnt vmcnt(0)" ::: "memory");
        __builtin_amdgcn_sched_barrier(0);

        floatx2 a01 = (floatx2){0.f, 0.f}, a23 = (floatx2){0.f, 0.f};
        floatx2 a45 = (floatx2){0.f, 0.f}, a67 = (floatx2){0.f, 0.f};
#pragma unroll
        for (int t = 0; t < 16; ++t) {
            const floatx2 wv2 = (floatx2){w[t], w[t]};
            a01 = pk_fma(unpack2(ld[t][0]), wv2, a01);
            a23 = pk_fma(unpack2(ld[t][1]), wv2, a23);
            a45 = pk_fma(unpack2(ld[t][2]), wv2, a45);
            a67 = pk_fma(unpack2(ld[t][3]), wv2, a67);
        }

        if (cell < NCELL) {
            uint4 o;
            o.x = pack2bf(a01.x, a01.y);
            o.y = pack2bf(a23.x, a23.y);
            o.z = pack2bf(a45.x, a45.y);
            o.w = pack2bf(a67.x, a67.y);
            *(uint4*)&rbase[c * HID] = o;
            As4[c * 32 + ((lane & 31) ^ (c & 7))] = o;   // swizzled LDS copy
        }
    }
    __syncthreads();

    // ---- p1 GEMM phase: (49->64) x 64 x 256, A exact-bf16 from LDS ----
    const int koff = (lane >> 4) * 8;      // ushort offset within 32-k chunk
    const int nidx = lane & 15;
    const int arow = wave * 16 + nidx;

    floatx4 acc[4];
#pragma unroll
    for (int t = 0; t < 4; ++t) acc[t] = (floatx4){0.f, 0.f, 0.f, 0.f};

    for (int k0 = 0; k0 < 256; k0 += 32) {
        const int chunk = (k0 >> 3) + (lane >> 4);
        short8 aH = *(short8*)&As4[arow * 32 + (chunk ^ (arow & 7))];
#pragma unroll
        for (int t = 0; t < 4; ++t) {
            const int wrow = t * 16 + nidx;
            short8 wHf = *(const short8*)(WH + (size_t)wrow * 256 + k0 + koff);
            short8 wLf = *(const short8*)(WL + (size_t)wrow * 256 + k0 + koff);
            acc[t] = __builtin_amdgcn_mfma_f32_16x16x32_bf16(aH, wHf, acc[t], 0, 0, 0);
            acc[t] = __builtin_amdgcn_mfma_f32_16x16x32_bf16(aH, wLf, acc[t], 0, 0, 0);
        }
    }

#pragma unroll
    for (int t = 0; t < 4; ++t) {
        const int n = t * 16 + nidx;
        const float bv = bias[n];
#pragma unroll
        for (int reg = 0; reg < 4; ++reg) {
            const int mt = wave * 16 + (lane >> 4) * 4 + reg;
            if (mt < NCELL) {
                float v = fmaxf(acc[t][reg] + bv, 0.f);
                ushort_t h, l;
                split_bf(v, h, l);
                const size_t m = (size_t)i2 * NCELL + mt;
                CH[m * 64 + n] = h;
                CL[m * 64 + n] = l;
            }
        }
    }
}

// ---------------------------------------------------------------------------
// Fused (round 20): gather vectorized 4x; logits conflict-free.
// ---------------------------------------------------------------------------
__global__ __launch_bounds__(256) void k_fuse(
    const ushort_t* __restrict__ roi, const float* __restrict__ pts,
    const float* __restrict__ gate, const float* __restrict__ w,
    const float* __restrict__ bias, float* __restrict__ out) {
    __shared__ float sm_qe[32 * HID];
    __shared__ float sm_hd[32][4];
    __shared__ float sm_l[32];
    __shared__ float sm_e[32];

    const int tid = threadIdx.x;
    const int r = blockIdx.x;

    if (tid < 32) {
        int lvl = tid >> 3, h = tid & 7;
        float gx = pts[((size_t)r * 4 + lvl) * 16 + h * 2];
        float gy = pts[((size_t)r * 4 + lvl) * 16 + h * 2 + 1];
        float ix = ((gx + 1.f) * 7.f - 1.f) * 0.5f;
        float iy = ((gy + 1.f) * 7.f - 1.f) * 0.5f;
        float x0f = floorf(ix), y0f = floorf(iy);
        sm_hd[tid][0] = x0f;
        sm_hd[tid][1] = y0f;
        sm_hd[tid][2] = ix - x0f;
        sm_hd[tid][3] = iy - y0f;
    }
    __syncthreads();

    // gather: wave wid handles j = wid*8..wid*8+7; lane owns channels 4*cq..
    {
        const int wid = tid >> 6;
        const int cq  = (tid & 63) * 4;
#pragma unroll
        for (int jj = 0; jj < 8; ++jj) {
            const int j = wid * 8 + jj;
            const int lvl = j >> 3, h = j & 7;
            const ushort_t* rbase = roi + ((size_t)r * 4 + lvl) * NCELL * HID + cq;
            const float x0f = sm_hd[j][0], y0f = sm_hd[j][1];
            const float lx = sm_hd[j][2], ly = sm_hd[j][3];
            const int x0 = (int)x0f, y0 = (int)y0f;
            float a0 = 0.f, a1 = 0.f, a2 = 0.f, a3 = 0.f;
#pragma unroll
            for (int dy = 0; dy < 2; ++dy) {
                const int yi = y0 + dy;
                if (yi < 0 || yi >= 7) continue;
                const float wy = dy ? ly : 1.f - ly;
#pragma unroll
                for (int dx = 0; dx < 2; ++dx) {
                    const int xi = x0 + dx;
                    if (xi < 0 || xi >= 7) continue;
                    const float wt = wy * (dx ? lx : 1.f - lx);
                    const ushort4 u = *(const ushort4*)&rbase[(yi * 7 + xi) * HID];
                    a0 += wt * bfbits2f(u.x);
                    a1 += wt * bfbits2f(u.y);
                    a2 += wt * bfbits2f(u.z);
                    a3 += wt * bfbits2f(u.w);
                }
            }
            const float4 g4 = *(const float4*)&gate[(size_t)r * 2048 + h * HID + cq];
            float4 qv;
            qv.x = a0 * g4.x; qv.y = a1 * g4.y;
            qv.z = a2 * g4.z; qv.w = a3 * g4.w;
            *(float4*)&sm_qe[j * HID + cq] = qv;
        }
    }
    __syncthreads();

    // logits: conflict-free — lane32 owns bank lane32; width-32 reduce.
    {
        const int jg = tid >> 5, lane32 = tid & 31;
#pragma unroll
        for (int p = 0; p < 4; ++p) {
            const int j = p * 8 + jg;
            float part = 0.f;
#pragma unroll
            for (int i = 0; i < 8; ++i)
                part += sm_qe[j * HID + lane32 + 32 * i] * w[lane32 + 32 * i];
            part += __shfl_down(part, 16, 32);
            part += __shfl_down(part, 8, 32);
            part += __shfl_down(part, 4, 32);
            part += __shfl_down(part, 2, 32);
            part += __shfl_down(part, 1, 32);
            if (lane32 == 0) sm_l[j] = part + bias[0];
        }
    }
    __syncthreads();
    if (tid < 32) {
        float m = -1e30f;
        for (int i = 0; i < 32; ++i) m = fmaxf(m, sm_l[i]);
        sm_e[tid] = expf(sm_l[tid] - m);
    }
    __syncthreads();
    float denom = 0.f;
    for (int i = 0; i < 32; ++i) denom += sm_e[i];
    float inv = 1.f / denom;
    float acc = 0.f;
    for (int jj = 0; jj < 32; ++jj) acc += sm_qe[jj * HID + tid] * sm_e[jj];
    out[(size_t)r * HID + tid] = acc * inv;
}

// ---------------------------------------------------------------------------
extern "C" void kernel_launch(void* const* d_in, const int* in_sizes, int n_in,
                              void* d_out, int out_size, void* d_ws, size_t ws_size,
                              hipStream_t stream) {
    const float* tgt    = (const float*)d_in[0];
    const float* memory = (const float*)d_in[1];
    const float* refr   = (const float*)d_in[2];
    const float* p1w = (const float*)d_in[4];
    const float* p1b = (const float*)d_in[5];
    const float* w1  = (const float*)d_in[6];
    const float* b1  = (const float*)d_in[7];
    const float* w2  = (const float*)d_in[8];
    const float* b2  = (const float*)d_in[9];
    const float* w3  = (const float*)d_in[10];
    const float* b3  = (const float*)d_in[11];
    const float* w4  = (const float*)d_in[12];
    const float* b4  = (const float*)d_in[13];
    const float* a1w = (const float*)d_in[14];
    const float* a1b = (const float*)d_in[15];
    const float* a2w = (const float*)d_in[16];
    const float* a2b = (const float*)d_in[17];
    float* out = (float*)d_out;

    size_t off = 0;
    auto alloc = [&](size_t bytes) {
        void* p = (char*)d_ws + off;
        off += (bytes + 255) & ~(size_t)255;
        return p;
    };
    float*    gate  = (float*)alloc((size_t)600 * 2048 * 4);
    ushort_t* mem16 = (ushort_t*)alloc((size_t)2 * TOTAL * HID * 2);
    ushort_t* roi   = (ushort_t*)alloc((size_t)2400 * NCELL * HID * 2);
    ushort_t* pHb   = (ushort_t*)alloc((size_t)2400 * 3136 * 2);
    ushort_t* pLb   = (ushort_t*)alloc((size_t)2400 * 3136 * 2);
    float*    h1p   = (float*)alloc((size_t)7 * 2400 * 256 * 4);
    ushort_t* h1H   = (ushort_t*)alloc((size_t)2400 * 256 * 2);
    ushort_t* h1L   = (ushort_t*)alloc((size_t)2400 * 256 * 2);
    ushort_t* h2H   = (ushort_t*)alloc((size_t)2400 * 512 * 2);
    ushort_t* h2L   = (ushort_t*)alloc((size_t)2400 * 512 * 2);
    float*    h3    = (float*)alloc((size_t)2400 * 512 * 4);
    float*    pts   = (float*)alloc((size_t)2400 * 16 * 4);
    ushort_t* tgtH  = (ushort_t*)alloc((size_t)600 * 256 * 2);
    ushort_t* tgtL  = (ushort_t*)alloc((size_t)600 * 256 * 2);
    ushort_t* a1wTH = (ushort_t*)alloc((size_t)2048 * 256 * 2);
    ushort_t* a1wTL = (ushort_t*)alloc((size_t)2048 * 256 * 2);
    ushort_t* w1TH  = (ushort_t*)alloc((size_t)256 * 3136 * 2);
    ushort_t* w1TL  = (ushort_t*)alloc((size_t)256 * 3136 * 2);
    ushort_t* w2TH  = (ushort_t*)alloc((size_t)512 * 256 * 2);
    ushort_t* w2TL  = (ushort_t*)alloc((size_t)512 * 256 * 2);
    ushort_t* w3TH  = (ushort_t*)alloc((size_t)512 * 512 * 2);
    ushort_t* w3TL  = (ushort_t*)alloc((size_t)512 * 512 * 2);
    ushort_t* p1wTH = (ushort_t*)alloc((size_t)64 * 256 * 2);
    ushort_t* p1wTL = (ushort_t*)alloc((size_t)64 * 256 * 2);

    // merged prep: 1024 range blocks + 10880 memory-conversion blocks
    hipLaunchKernelGGL(k_prep, dim3(11904), dim3(256), 0, stream,
                       tgt, tgtH, tgtL, a1w, a1wTH, a1wTL,
                       w1, w1TH, w1TL, w2, w2TH, w2TL, w3, w3TH, w3TL,
                       p1w, p1wTH, p1wTL, memory, mem16);

    // gate = sigmoid(tgt @ a1w + a1b)   [W-resident GEMM, M-tile 128]
    hipLaunchKernelGGL((k_wres<2, 0, 256, 64>), dim3(5 * 32), dim3(256), 0, stream,
                       tgtH, tgtL, a1wTH, a1wTL, a1b, gate, (ushort_t*)0, (ushort_t*)0,
                       600, 2048, 5);
    // roi + p1 fused: 2400 blocks, level-interleaved
    hipLaunchKernelGGL(k_roip1, dim3(2400), dim3(256), 0, stream,
                       mem16, refr, roi, p1wTH, p1wTL, p1b, pHb, pLb);
    // w1 GEMM: split-K x7, 64x128 tile
    hipLaunchKernelGGL(k_w1, dim3(38, 2, 7), dim3(256), 0, stream,
                       pHb, pLb, w1TH, w1TL, h1p, 2400, 256, 3136, 448);
    hipLaunchKernelGGL(k_h1red, dim3(600), dim3(256), 0, stream, h1p, b1, h1H, h1L);
    // w2 (2400 x 512, K=256)   [W-resident]
    hipLaunchKernelGGL((k_wres<0, 0, 256, 64>), dim3(19 * 8), dim3(256), 0, stream,
                       h1H, h1L, w2TH, w2TL, b2, (float*)0, h2H, h2L, 2400, 512, 19);
    // w3 (2400 x 512, K=512)   [W-resident, NT=32]
    hipLaunchKernelGGL((k_wres<1, 0, 512, 32>), dim3(19 * 16), dim3(256), 0, stream,
                       h2H, h2L, w3TH, w3TL, b3, h3, (ushort_t*)0, (ushort_t*)0,
                       2400, 512, 19);
    // pts = tanh(h3 @ w4 + b4)
    hipLaunchKernelGGL(k_pts, dim3(600), dim3(256), 0, stream, h3, w4, b4, pts);
    // fused sample + softmax-output (vectorized gather)
    hipLaunchKernelGGL(k_fuse, dim3(600), dim3(256), 0, stream,
                       roi, pts, gate, a2w, a2b, out);
}

// Round 13
// 315.292 us; speedup vs baseline: 1.1849x; 1.1849x over previous
//
#include <hip/hip_runtime.h>
#include <hip/hip_bf16.h>

#define NQ     300
#define NH     8
#define HID    256
#define NLVL   4
#define NCELL  49
#define TOTAL  21760

typedef unsigned short ushort_t;
typedef __attribute__((ext_vector_type(8))) short short8;
typedef __attribute__((ext_vector_type(4))) float floatx4;
typedef __attribute__((ext_vector_type(2))) float floatx2;
typedef __attribute__((ext_vector_type(4))) unsigned int uintx4;

__device__ __forceinline__ float bfbits2f(ushort_t u) {
    union { unsigned int i; float f; } x;
    x.i = ((unsigned int)u) << 16;
    return x.f;
}
__device__ __forceinline__ ushort_t f2bfbits(float v) {
    __hip_bfloat16 h = __float2bfloat16(v);
    return *(ushort_t*)&h;
}
__device__ __forceinline__ unsigned int pack2bf(float a, float b) {
    return (unsigned int)f2bfbits(a) | ((unsigned int)f2bfbits(b) << 16);
}
__device__ __forceinline__ void split_bf(float v, ushort_t& hi, ushort_t& lo) {
    __hip_bfloat16 h = __float2bfloat16(v);
    hi = *(ushort_t*)&h;
    float hv = __bfloat162float(h);
    __hip_bfloat16 l = __float2bfloat16(v - hv);
    lo = *(ushort_t*)&l;
}

// packed f32 FMA: 2 FMAs per issue slot (CDNA v_pk_fma_f32)
__device__ __forceinline__ floatx2 pk_fma(floatx2 a, floatx2 b, floatx2 c) {
    floatx2 d;
    asm("v_pk_fma_f32 %0, %1, %2, %3" : "=v"(d) : "v"(a), "v"(b), "v"(c));
    return d;
}
// uint (2 packed bf16) -> {lo, hi} as exact f32 pair
__device__ __forceinline__ floatx2 unpack2(unsigned int u) {
    union { unsigned int i; float f; } lo, hi;
    lo.i = u << 16;
    hi.i = u & 0xffff0000u;
    return (floatx2){lo.f, hi.f};
}
// explicit async 16B load (k_roi): issued in program order, untracked by the
// compiler's waitcnt insertion. Valid only after s_waitcnt vmcnt(0)+sched_barrier.
__device__ __forceinline__ uintx4 ld_async_b128(const ushort_t* p) {
    uintx4 d;
    asm volatile("global_load_dwordx4 %0, %1, off" : "=v"(d) : "v"(p));
    return d;
}

// ---------------------------------------------------------------------------
// ROI helpers — bf16 memory (validated rounds 9-10)
// ---------------------------------------------------------------------------
struct Box {
    float sx, sy, bw, bh, Wf;
    int W;
    const ushort_t* memb;
};

__device__ __forceinline__ void load_box(const float* __restrict__ refr,
                                         const ushort_t* __restrict__ mem16,
                                         int r, int lvl, int ch, Box& bx) {
    const int lvl_hw[4] = {128, 64, 32, 16};
    const int lvl_s[4]  = {0, 16384, 20480, 21504};
    const int b = r / NQ;
    bx.W  = lvl_hw[lvl];
    bx.Wf = (float)bx.W;
    const float* rp = refr + ((size_t)r * NLVL + lvl) * 6;
    float cx = rp[0], cy = rp[1];
    float dl = rp[2], dt = rp[3], dr = rp[4], db = rp[5];
    float x1 = fminf(fmaxf(cx - dl, 0.f), 1.f) * bx.Wf;
    float y1 = fminf(fmaxf(cy - dt, 0.f), 1.f) * bx.Wf;
    float x2 = fminf(fmaxf(cx + dr, 0.f), 1.f) * bx.Wf;
    float y2 = fminf(fmaxf(cy + db, 0.f), 1.f) * bx.Wf;
    bx.sx = x1 - 0.5f;
    bx.sy = y1 - 0.5f;
    bx.bw = (x2 - x1) * (1.f / 7.f);
    bx.bh = (y2 - y1) * (1.f / 7.f);
    bx.memb = mem16 + ((size_t)b * TOTAL + lvl_s[lvl]) * HID + ch;
}

// ---------------------------------------------------------------------------
// Merged prep: esplit(tgt) + 5x tsplit + memory->bf16  (one launch)
// ---------------------------------------------------------------------------
__device__ __forceinline__ void tsplit_body(const float* __restrict__ W,
                                            ushort_t* __restrict__ TH,
                                            ushort_t* __restrict__ TL,
                                            int K, int N, int kb, int nb,
                                            int perm, int tid, float (*sm)[65]) {
    for (int e = tid; e < 64 * 64; e += 256) {
        int kk = e >> 6, nn = e & 63;
        int kp = kb + kk;
        int ks = perm ? ((kp & 63) * 49 + (kp >> 6)) : kp;
        sm[kk][nn] = W[(size_t)ks * N + nb + nn];
    }
    __syncthreads();
    for (int e = tid; e < 64 * 64; e += 256) {
        int nn = e >> 6, kk = e & 63;
        ushort_t h, l;
        split_bf(sm[kk][nn], h, l);
        size_t o = (size_t)(nb + nn) * K + kb + kk;
        TH[o] = h; TL[o] = l;
    }
}

__global__ __launch_bounds__(256) void k_prep(
    const float* __restrict__ tgt, ushort_t* __restrict__ tgtH, ushort_t* __restrict__ tgtL,
    const float* __restrict__ a1w, ushort_t* __restrict__ a1wTH, ushort_t* __restrict__ a1wTL,
    const float* __restrict__ w1, ushort_t* __restrict__ w1TH, ushort_t* __restrict__ w1TL,
    const float* __restrict__ w2, ushort_t* __restrict__ w2TH, ushort_t* __restrict__ w2TL,
    const float* __restrict__ w3, ushort_t* __restrict__ w3TH, ushort_t* __restrict__ w3TL,
    const float* __restrict__ p1w, ushort_t* __restrict__ p1wTH, ushort_t* __restrict__ p1wTL,
    const float* __restrict__ memory, ushort_t* __restrict__ mem16) {
    __shared__ float sm[64][65];
    const int tid = threadIdx.x;
    int b = blockIdx.x;
    if (b < 600) {                       // esplit on tgt (600*256 elems)
        int i = b * 256 + tid;
        ushort_t h, l;
        split_bf(tgt[i], h, l);
        tgtH[i] = h; tgtL[i] = l;
    } else if (b < 728) {                // a1w: K=256 x N=2048
        b -= 600;
        tsplit_body(a1w, a1wTH, a1wTL, 256, 2048, (b % 4) * 64, (b / 4) * 64, 0, tid, sm);
    } else if (b < 924) {                // w1: K=3136 x N=256, PERM
        b -= 728;
        tsplit_body(w1, w1TH, w1TL, 3136, 256, (b % 49) * 64, (b / 49) * 64, 1, tid, sm);
    } else if (b < 956) {                // w2: K=256 x N=512
        b -= 924;
        tsplit_body(w2, w2TH, w2TL, 256, 512, (b % 4) * 64, (b / 4) * 64, 0, tid, sm);
    } else if (b < 1020) {               // w3: K=512 x N=512
        b -= 956;
        tsplit_body(w3, w3TH, w3TL, 512, 512, (b % 8) * 64, (b / 8) * 64, 0, tid, sm);
    } else if (b < 1024) {               // p1w: K=256 x N=64
        b -= 1020;
        tsplit_body(p1w, p1wTH, p1wTL, 256, 64, b * 64, 0, 0, tid, sm);
    } else {                             // memory -> bf16 (10880 blocks)
        b -= 1024;
        size_t i = (size_t)b * 256 + tid;   // float4 index
        float4 v = ((const float4*)memory)[i];
        ushort4 o;
        o.x = f2bfbits(v.x); o.y = f2bfbits(v.y);
        o.z = f2bfbits(v.z); o.w = f2bfbits(v.w);
        ((ushort4*)mem16)[i] = o;
    }
}

// ---------------------------------------------------------------------------
// bf16x3 MFMA GEMM, 64x64 tile — used for w1 split-K.  EPI 3 = split-K partial.
// ---------------------------------------------------------------------------
template <int EPI, int AX>
__global__ __launch_bounds__(256) void k_gmfma(
    const ushort_t* __restrict__ AH, const ushort_t* __restrict__ AL,
    const ushort_t* __restrict__ WH, const ushort_t* __restrict__ WL,
    const float* __restrict__ bias, float* __restrict__ Cf,
    ushort_t* __restrict__ CH, ushort_t* __restrict__ CL,
    int M, int N, int K, int kchunk) {
    __shared__ ushort_t As[AX ? 1 : 2][64][40];
    __shared__ ushort_t Ws[2][64][40];

    const int tid = threadIdx.x;
    const int m0 = blockIdx.x * 64, n0 = blockIdx.y * 64;
    const int wv = tid >> 6, ln = tid & 63;
    const int row = tid >> 2, kc = tid & 3;
    const int gm = min(m0 + row, M - 1);
    const int gn = n0 + row;
    const int arow = wv * 16 + (ln & 15);
    const int koff = (ln >> 4) * 8;

    int kb = 0, ke = K;
    if (EPI == 3) {
        kb = blockIdx.z * kchunk;
        ke = min(K, kb + kchunk);
    }

    floatx4 acc[4];
#pragma unroll
    for (int t = 0; t < 4; ++t) acc[t] = (floatx4){0.f, 0.f, 0.f, 0.f};

    for (int k0 = kb; k0 < ke; k0 += 32) {
        *(uint4*)&As[0][row][kc * 8] = *(const uint4*)(AH + (size_t)gm * K + k0 + kc * 8);
        if constexpr (!AX)
            *(uint4*)&As[AX ? 0 : 1][row][kc * 8] = *(const uint4*)(AL + (size_t)gm * K + k0 + kc * 8);
        *(uint4*)&Ws[0][row][kc * 8] = *(const uint4*)(WH + (size_t)gn * K + k0 + kc * 8);
        *(uint4*)&Ws[1][row][kc * 8] = *(const uint4*)(WL + (size_t)gn * K + k0 + kc * 8);
        __syncthreads();

        short8 aH = *(short8*)&As[0][arow][koff];
        short8 aL = aH;
        if constexpr (!AX) aL = *(short8*)&As[AX ? 0 : 1][arow][koff];
#pragma unroll
        for (int t = 0; t < 4; ++t) {
            short8 wH = *(short8*)&Ws[0][t * 16 + (ln & 15)][koff];
            short8 wL = *(short8*)&Ws[1][t * 16 + (ln & 15)][koff];
            acc[t] = __builtin_amdgcn_mfma_f32_16x16x32_bf16(aH, wH, acc[t], 0, 0, 0);
            acc[t] = __builtin_amdgcn_mfma_f32_16x16x32_bf16(aH, wL, acc[t], 0, 0, 0);
            if constexpr (!AX)
                acc[t] = __builtin_amdgcn_mfma_f32_16x16x32_bf16(aL, wH, acc[t], 0, 0, 0);
        }
        __syncthreads();
    }

    float* Cpart = (EPI == 3) ? Cf + (size_t)blockIdx.z * M * N : Cf;
#pragma unroll
    for (int t = 0; t < 4; ++t) {
        int n = n0 + t * 16 + (ln & 15);
        float bv = (EPI == 3) ? 0.f : bias[n];
#pragma unroll
        for (int reg = 0; reg < 4; ++reg) {
            int m = m0 + wv * 16 + (ln >> 4) * 4 + reg;
            if (m < M) {
                float v = acc[t][reg] + bv;
                if (EPI == 0) {
                    v = fmaxf(v, 0.f);
                    ushort_t h, l;
                    split_bf(v, h, l);
                    CH[(size_t)m * N + n] = h;
                    CL[(size_t)m * N + n] = l;
                } else if (EPI == 1) {
                    Cf[(size_t)m * N + n] = fmaxf(v, 0.f);
                } else if (EPI == 2) {
                    Cf[(size_t)m * N + n] = 1.f / (1.f + expf(-v));
                } else {
                    Cpart[(size_t)m * N + n] = v;
                }
            }
        }
    }
}

// ---------------------------------------------------------------------------
// W-resident GEMM for small-W shapes (p1/gate/w2/w3) — validated round 6.
// ---------------------------------------------------------------------------
template <int EPI, int AX, int KK, int NT>
__global__ __launch_bounds__(256) void k_wres(
    const ushort_t* __restrict__ AH, const ushort_t* __restrict__ AL,
    const ushort_t* __restrict__ WH, const ushort_t* __restrict__ WL,
    const float* __restrict__ bias, float* __restrict__ Cf,
    ushort_t* __restrict__ CH, ushort_t* __restrict__ CL,
    int M, int N, int nbm) {
    constexpr int KC = KK / 8;                 // 16B chunks per W row
    __shared__ ushort_t Wls[2 * NT * KK];      // 64 KB for both configs

    const int tid = threadIdx.x;
    const int m0 = (blockIdx.x % nbm) * 128;
    const int n0 = (blockIdx.x / nbm) * NT;

    // stage W rows n0..n0+NT-1 (full K), hi then lo, XOR-swizzled chunks
    {
        const uint4* sH = (const uint4*)(WH + (size_t)n0 * KK);
        const uint4* sL = (const uint4*)(WL + (size_t)n0 * KK);
        uint4* d = (uint4*)Wls;
        for (int i = tid; i < NT * KC; i += 256) {
            const int nn = i / KC, kk = i % KC;
            const int sw = nn * KC + (kk ^ (nn & 7));
            d[sw] = sH[i];
            d[NT * KC + sw] = sL[i];
        }
    }
    __syncthreads();

    const int wv = tid >> 6, ln = tid & 63;
    const int koff = (ln >> 4) * 8, nidx = ln & 15;
    const size_t a0 = (size_t)min(m0 + wv * 16 + (ln & 15), M - 1) * KK;
    const size_t a1 = (size_t)min(m0 + 64 + wv * 16 + (ln & 15), M - 1) * KK;

    floatx4 acc[2][NT / 16];
#pragma unroll
    for (int s = 0; s < 2; ++s)
#pragma unroll
        for (int t = 0; t < NT / 16; ++t) acc[s][t] = (floatx4){0.f, 0.f, 0.f, 0.f};

    for (int k0 = 0; k0 < KK; k0 += 32) {
        short8 a0H = *(const short8*)(AH + a0 + k0 + koff);
        short8 a1H = *(const short8*)(AH + a1 + k0 + koff);
        short8 a0L = a0H, a1L = a1H;
        if constexpr (!AX) {
            a0L = *(const short8*)(AL + a0 + k0 + koff);
            a1L = *(const short8*)(AL + a1 + k0 + koff);
        }
        const int kc = (k0 + koff) >> 3;
#pragma unroll
        for (int t = 0; t < NT / 16; ++t) {
            const int wrow = t * 16 + nidx;
            const int swr = wrow * KC + (kc ^ (wrow & 7));
            short8 wHf = *(const short8*)((const uint4*)Wls + swr);
            short8 wLf = *(const short8*)((const uint4*)Wls + NT * KC + swr);
            acc[0][t] = __builtin_amdgcn_mfma_f32_16x16x32_bf16(a0H, wHf, acc[0][t], 0, 0, 0);
            acc[0][t] = __builtin_amdgcn_mfma_f32_16x16x32_bf16(a0H, wLf, acc[0][t], 0, 0, 0);
            if constexpr (!AX)
                acc[0][t] = __builtin_amdgcn_mfma_f32_16x16x32_bf16(a0L, wHf, acc[0][t], 0, 0, 0);
            acc[1][t] = __builtin_amdgcn_mfma_f32_16x16x32_bf16(a1H, wHf, acc[1][t], 0, 0, 0);
            acc[1][t] = __builtin_amdgcn_mfma_f32_16x16x32_bf16(a1H, wLf, acc[1][t], 0, 0, 0);
            if constexpr (!AX)
                acc[1][t] = __builtin_amdgcn_mfma_f32_16x16x32_bf16(a1L, wHf, acc[1][t], 0, 0, 0);
        }
    }

#pragma unroll
    for (int s = 0; s < 2; ++s)
#pragma unroll
        for (int t = 0; t < NT / 16; ++t) {
            const int n = n0 + t * 16 + nidx;
            const float bv = bias[n];
#pragma unroll
            for (int reg = 0; reg < 4; ++reg) {
                const int m = m0 + s * 64 + wv * 16 + (ln >> 4) * 4 + reg;
                if (m < M) {
                    float v = acc[s][t][reg] + bv;
                    if constexpr (EPI == 0) {
                        v = fmaxf(v, 0.f);
                        ushort_t h, l;
                        split_bf(v, h, l);
                        CH[(size_t)m * N + n] = h;
                        CL[(size_t)m * N + n] = l;
                    } else if constexpr (EPI == 1) {
                        Cf[(size_t)m * N + n] = fmaxf(v, 0.f);
                    } else {
                        Cf[(size_t)m * N + n] = 1.f / (1.f + expf(-v));
                    }
                }
            }
        }
}

// ---------------------------------------------------------------------------
// Split-K reduction for h1: sum 7 partials + bias, relu, hi/lo split.
// ---------------------------------------------------------------------------
__global__ __launch_bounds__(256) void k_h1red(
    const float* __restrict__ h1p, const float* __restrict__ b1,
    ushort_t* __restrict__ h1H, ushort_t* __restrict__ h1L) {
    const int idx = blockIdx.x * 256 + threadIdx.x;    // float4 index
    const int n = (idx * 4) & 255;
    float4 s = ((const float4*)h1p)[idx];
#pragma unroll
    for (int z = 1; z < 7; ++z) {
        float4 t = ((const float4*)(h1p + (size_t)z * 2400 * 256))[idx];
        s.x += t.x; s.y += t.y; s.z += t.z; s.w += t.w;
    }
    float4 bv = *(const float4*)(b1 + n);
    s.x = fmaxf(s.x + bv.x, 0.f);
    s.y = fmaxf(s.y + bv.y, 0.f);
    s.z = fmaxf(s.z + bv.z, 0.f);
    s.w = fmaxf(s.w + bv.w, 0.f);
    ushort4 H, L;
    split_bf(s.x, H.x, L.x);
    split_bf(s.y, H.y, L.y);
    split_bf(s.z, H.z, L.z);
    split_bf(s.w, H.w, L.w);
    ((ushort4*)h1H)[idx] = H;
    ((ushort4*)h1L)[idx] = L;
}

// ---------------------------------------------------------------------------
// pts = tanh(h3 @ w4 + b4): (2400 x 512) @ (512 x 16). Hoisted from k_fuse
// (round 19). w4 staged in LDS; same split-4 shfl reduction order ->
// bit-identical pts.
// ---------------------------------------------------------------------------
__global__ __launch_bounds__(256) void k_pts(
    const float* __restrict__ h3, const float* __restrict__ w4,
    const float* __restrict__ b4, float* __restrict__ pts) {
    __shared__ float w4s[512 * 16];
    const int tid = threadIdx.x;
    for (int i = tid; i < 512 * 16 / 4; i += 256)
        ((float4*)w4s)[i] = ((const float4*)w4)[i];
    __syncthreads();

    const int row = blockIdx.x * 4 + (tid >> 6);   // 4 h3-rows per block
    const int col = (tid >> 2) & 15;
    const int ks  = tid & 3;
    const float* hrow = h3 + (size_t)row * 512 + ks * 128;
    float part = 0.f;
    for (int k = 0; k < 128; ++k)
        part += hrow[k] * w4s[(ks * 128 + k) * 16 + col];
    part += __shfl_down(part, 2);
    part += __shfl_down(part, 1);
    if (ks == 0) pts[row * 16 + col] = tanhf(part + b4[col]);
}

// ---------------------------------------------------------------------------
// Per instance: ROI-align only -> roi bf16 global. (round-4 structure)
// Round 23: reverted from the round-22 p1 fusion — the in-block barrier
// serialized gather/GEMM phases and the 32KB LDS cut resident gather waves;
// two dispatches overlap at wave level for free (m114).
// ---------------------------------------------------------------------------
__global__ __launch_bounds__(256) void k_roi(
    const ushort_t* __restrict__ mem16, const float* __restrict__ refr,
    ushort_t* __restrict__ roi) {
    const int tid  = threadIdx.x;
    const int wave = tid >> 6, lane = tid & 63;
    const int half = lane >> 5;            // which cell of the pair
    const int chv  = (lane & 31) * 8;      // 8 channels per lane
    const int bid  = blockIdx.x;

    int lvl, r, klo, khi;
    if (bid < 1200) {                      // lvl 0, 2 blocks per ROI (slowest first)
        lvl = 0; r = bid >> 1;
        klo = (bid & 1) ? 13 : 0; khi = (bid & 1) ? 25 : 13;
    } else if (bid < 2400) {               // lvl 1, 2 blocks per ROI
        const int t = bid - 1200;
        lvl = 1; r = t >> 1;
        klo = (t & 1) ? 13 : 0; khi = (t & 1) ? 25 : 13;
    } else if (bid < 3000) {               // lvl 2, whole ROI
        lvl = 2; r = bid - 2400; klo = 0; khi = 25;
    } else {                               // lvl 3, whole ROI
        lvl = 3; r = bid - 3000; klo = 0; khi = 25;
    }
    const int i2 = r * 4 + lvl;

    Box bx;
    load_box(refr, mem16, r, lvl, chv, bx);
    const int rowstride = bx.W * HID;

    ushort_t* rbase = roi + (size_t)i2 * NCELL * HID + chv;

    // cell-pairs: pair k covers cells {2k, 2k+1}; pair 24 has only cell 48.
    for (int k = klo + wave; k < khi; k += 4) {
        const int cell = 2 * k + half;
        const int c = (cell < NCELL) ? cell : (NCELL - 1);
        const int ph = c / 7, pw = c % 7;

        uintx4 ld[16];
        float  w[16];
#pragma unroll
        for (int sub = 0; sub < 4; ++sub) {
            const float tys = (float)ph + ((sub >> 1) + 0.5f) * 0.5f;
            const float txs = (float)pw + ((sub & 1) + 0.5f) * 0.5f;
            const float yy = bx.sy + bx.bh * tys;
            const float xx = bx.sx + bx.bw * txs;
            const float vm = (yy >= -1.f && yy <= bx.Wf && xx <= bx.Wf && xx >= -1.f)
                             ? 0.25f : 0.f;
            const float yc  = fminf(fmaxf(yy, 0.f), bx.Wf - 1.f);
            const float xc  = fminf(fmaxf(xx, 0.f), bx.Wf - 1.f);
            const float y0f = fminf(floorf(yc), bx.Wf - 2.f);
            const float x0f = fminf(floorf(xc), bx.Wf - 2.f);
            const float ly = yc - y0f, lx = xc - x0f;
            const int   y0 = (int)y0f, x0 = (int)x0f;
            const ushort_t* p00 = bx.memb + (y0 * bx.W + x0) * HID;
            ld[sub * 4 + 0] = ld_async_b128(p00);
            ld[sub * 4 + 1] = ld_async_b128(p00 + HID);
            ld[sub * 4 + 2] = ld_async_b128(p00 + rowstride);
            ld[sub * 4 + 3] = ld_async_b128(p00 + rowstride + HID);
            const float omy = 1.f - ly, omx = 1.f - lx;
            w[sub * 4 + 0] = vm * omy * omx;
            w[sub * 4 + 1] = vm * omy * lx;
            w[sub * 4 + 2] = vm * ly  * omx;
            w[sub * 4 + 3] = vm * ly  * lx;
        }

        asm volatile("s_waitcnt vmcnt(0)" ::: "memory");
        __builtin_amdgcn_sched_barrier(0);

        floatx2 a01 = (floatx2){0.f, 0.f}, a23 = (floatx2){0.f, 0.f};
        floatx2 a45 = (floatx2){0.f, 0.f}, a67 = (floatx2){0.f, 0.f};
#pragma unroll
        for (int t = 0; t < 16; ++t) {
            const floatx2 wv2 = (floatx2){w[t], w[t]};
            a01 = pk_fma(unpack2(ld[t][0]), wv2, a01);
            a23 = pk_fma(unpack2(ld[t][1]), wv2, a23);
            a45 = pk_fma(unpack2(ld[t][2]), wv2, a45);
            a67 = pk_fma(unpack2(ld[t][3]), wv2, a67);
        }

        if (cell < NCELL) {
            uint4 o;
            o.x = pack2bf(a01.x, a01.y);
            o.y = pack2bf(a23.x, a23.y);
            o.z = pack2bf(a45.x, a45.y);
            o.w = pack2bf(a67.x, a67.y);
            *(uint4*)&rbase[c * HID] = o;
        }
    }
}

// ---------------------------------------------------------------------------
// Fused (round 20): gather vectorized 4x — each wave owns 8 j, each lane
// owns 4 channels (ushort4 taps, 512B/wave/load). Logits conflict-free.
// ---------------------------------------------------------------------------
__global__ __launch_bounds__(256) void k_fuse(
    const ushort_t* __restrict__ roi, const float* __restrict__ pts,
    const float* __restrict__ gate, const float* __restrict__ w,
    const float* __restrict__ bias, float* __restrict__ out) {
    __shared__ float sm_qe[32 * HID];
    __shared__ float sm_hd[32][4];
    __shared__ float sm_l[32];
    __shared__ float sm_e[32];

    const int tid = threadIdx.x;
    const int r = blockIdx.x;

    if (tid < 32) {
        int lvl = tid >> 3, h = tid & 7;
        float gx = pts[((size_t)r * 4 + lvl) * 16 + h * 2];
        float gy = pts[((size_t)r * 4 + lvl) * 16 + h * 2 + 1];
        float ix = ((gx + 1.f) * 7.f - 1.f) * 0.5f;
        float iy = ((gy + 1.f) * 7.f - 1.f) * 0.5f;
        float x0f = floorf(ix), y0f = floorf(iy);
        sm_hd[tid][0] = x0f;
        sm_hd[tid][1] = y0f;
        sm_hd[tid][2] = ix - x0f;
        sm_hd[tid][3] = iy - y0f;
    }
    __syncthreads();

    // gather: wave wid handles j = wid*8..wid*8+7; lane owns channels 4*cq..
    {
        const int wid = tid >> 6;
        const int cq  = (tid & 63) * 4;
#pragma unroll
        for (int jj = 0; jj < 8; ++jj) {
            const int j = wid * 8 + jj;
            const int lvl = j >> 3, h = j & 7;
            const ushort_t* rbase = roi + ((size_t)r * 4 + lvl) * NCELL * HID + cq;
            const float x0f = sm_hd[j][0], y0f = sm_hd[j][1];
            const float lx = sm_hd[j][2], ly = sm_hd[j][3];
            const int x0 = (int)x0f, y0 = (int)y0f;
            float a0 = 0.f, a1 = 0.f, a2 = 0.f, a3 = 0.f;
#pragma unroll
            for (int dy = 0; dy < 2; ++dy) {
                const int yi = y0 + dy;
                if (yi < 0 || yi >= 7) continue;
                const float wy = dy ? ly : 1.f - ly;
#pragma unroll
                for (int dx = 0; dx < 2; ++dx) {
                    const int xi = x0 + dx;
                    if (xi < 0 || xi >= 7) continue;
                    const float wt = wy * (dx ? lx : 1.f - lx);
                    const ushort4 u = *(const ushort4*)&rbase[(yi * 7 + xi) * HID];
                    a0 += wt * bfbits2f(u.x);
                    a1 += wt * bfbits2f(u.y);
                    a2 += wt * bfbits2f(u.z);
                    a3 += wt * bfbits2f(u.w);
                }
            }
            const float4 g4 = *(const float4*)&gate[(size_t)r * 2048 + h * HID + cq];
            float4 qv;
            qv.x = a0 * g4.x; qv.y = a1 * g4.y;
            qv.z = a2 * g4.z; qv.w = a3 * g4.w;
            *(float4*)&sm_qe[j * HID + cq] = qv;
        }
    }
    __syncthreads();

    // logits: conflict-free — lane32 owns bank lane32; width-32 reduce.
    {
        const int jg = tid >> 5, lane32 = tid & 31;
#pragma unroll
        for (int p = 0; p < 4; ++p) {
            const int j = p * 8 + jg;
            float part = 0.f;
#pragma unroll
            for (int i = 0; i < 8; ++i)
                part += sm_qe[j * HID + lane32 + 32 * i] * w[lane32 + 32 * i];
            part += __shfl_down(part, 16, 32);
            part += __shfl_down(part, 8, 32);
            part += __shfl_down(part, 4, 32);
            part += __shfl_down(part, 2, 32);
            part += __shfl_down(part, 1, 32);
            if (lane32 == 0) sm_l[j] = part + bias[0];
        }
    }
    __syncthreads();
    if (tid < 32) {
        float m = -1e30f;
        for (int i = 0; i < 32; ++i) m = fmaxf(m, sm_l[i]);
        sm_e[tid] = expf(sm_l[tid] - m);
    }
    __syncthreads();
    float denom = 0.f;
    for (int i = 0; i < 32; ++i) denom += sm_e[i];
    float inv = 1.f / denom;
    float acc = 0.f;
    for (int jj = 0; jj < 32; ++jj) acc += sm_qe[jj * HID + tid] * sm_e[jj];
    out[(size_t)r * HID + tid] = acc * inv;
}

// ---------------------------------------------------------------------------
extern "C" void kernel_launch(void* const* d_in, const int* in_sizes, int n_in,
                              void* d_out, int out_size, void* d_ws, size_t ws_size,
                              hipStream_t stream) {
    const float* tgt    = (const float*)d_in[0];
    const float* memory = (const float*)d_in[1];
    const float* refr   = (const float*)d_in[2];
    const float* p1w = (const float*)d_in[4];
    const float* p1b = (const float*)d_in[5];
    const float* w1  = (const float*)d_in[6];
    const float* b1  = (const float*)d_in[7];
    const float* w2  = (const float*)d_in[8];
    const float* b2  = (const float*)d_in[9];
    const float* w3  = (const float*)d_in[10];
    const float* b3  = (const float*)d_in[11];
    const float* w4  = (const float*)d_in[12];
    const float* b4  = (const float*)d_in[13];
    const float* a1w = (const float*)d_in[14];
    const float* a1b = (const float*)d_in[15];
    const float* a2w = (const float*)d_in[16];
    const float* a2b = (const float*)d_in[17];
    float* out = (float*)d_out;

    size_t off = 0;
    auto alloc = [&](size_t bytes) {
        void* p = (char*)d_ws + off;
        off += (bytes + 255) & ~(size_t)255;
        return p;
    };
    float*    gate  = (float*)alloc((size_t)600 * 2048 * 4);
    ushort_t* mem16 = (ushort_t*)alloc((size_t)2 * TOTAL * HID * 2);
    ushort_t* roi   = (ushort_t*)alloc((size_t)2400 * NCELL * HID * 2);
    ushort_t* pHb   = (ushort_t*)alloc((size_t)2400 * 3136 * 2);
    ushort_t* pLb   = (ushort_t*)alloc((size_t)2400 * 3136 * 2);
    float*    h1p   = (float*)alloc((size_t)7 * 2400 * 256 * 4);
    ushort_t* h1H   = (ushort_t*)alloc((size_t)2400 * 256 * 2);
    ushort_t* h1L   = (ushort_t*)alloc((size_t)2400 * 256 * 2);
    ushort_t* h2H   = (ushort_t*)alloc((size_t)2400 * 512 * 2);
    ushort_t* h2L   = (ushort_t*)alloc((size_t)2400 * 512 * 2);
    float*    h3    = (float*)alloc((size_t)2400 * 512 * 4);
    float*    pts   = (float*)alloc((size_t)2400 * 16 * 4);
    ushort_t* tgtH  = (ushort_t*)alloc((size_t)600 * 256 * 2);
    ushort_t* tgtL  = (ushort_t*)alloc((size_t)600 * 256 * 2);
    ushort_t* a1wTH = (ushort_t*)alloc((size_t)2048 * 256 * 2);
    ushort_t* a1wTL = (ushort_t*)alloc((size_t)2048 * 256 * 2);
    ushort_t* w1TH  = (ushort_t*)alloc((size_t)256 * 3136 * 2);
    ushort_t* w1TL  = (ushort_t*)alloc((size_t)256 * 3136 * 2);
    ushort_t* w2TH  = (ushort_t*)alloc((size_t)512 * 256 * 2);
    ushort_t* w2TL  = (ushort_t*)alloc((size_t)512 * 256 * 2);
    ushort_t* w3TH  = (ushort_t*)alloc((size_t)512 * 512 * 2);
    ushort_t* w3TL  = (ushort_t*)alloc((size_t)512 * 512 * 2);
    ushort_t* p1wTH = (ushort_t*)alloc((size_t)64 * 256 * 2);
    ushort_t* p1wTL = (ushort_t*)alloc((size_t)64 * 256 * 2);

    // merged prep: 1024 range blocks + 10880 memory-conversion blocks
    hipLaunchKernelGGL(k_prep, dim3(11904), dim3(256), 0, stream,
                       tgt, tgtH, tgtL, a1w, a1wTH, a1wTL,
                       w1, w1TH, w1TL, w2, w2TH, w2TL, w3, w3TH, w3TL,
                       p1w, p1wTH, p1wTL, memory, mem16);

    // gate = sigmoid(tgt @ a1w + a1b)   [W-resident GEMM, M-tile 128]
    hipLaunchKernelGGL((k_wres<2, 0, 256, 64>), dim3(5 * 32), dim3(256), 0, stream,
                       tgtH, tgtL, a1wTH, a1wTL, a1b, gate, (ushort_t*)0, (ushort_t*)0,
                       600, 2048, 5);
    // roi: single dispatch (lvl0/1 split 2-blocks, LJF order)
    hipLaunchKernelGGL(k_roi, dim3(3600), dim3(256), 0, stream, mem16, refr, roi);
    // p1: (117600 x 256) @ (256 x 64), A exact-bf16   [W-resident]
    hipLaunchKernelGGL((k_wres<0, 1, 256, 64>), dim3(919), dim3(256), 0, stream,
                       roi, (ushort_t*)0, p1wTH, p1wTL, p1b, (float*)0, pHb, pLb,
                       2400 * NCELL, 64, 919);
    // w1 GEMM: split-K x7 (kchunk=448) -> partials -> reduce
    hipLaunchKernelGGL((k_gmfma<3, 0>), dim3(38, 4, 7), dim3(256), 0, stream,
                       pHb, pLb, w1TH, w1TL, (float*)0, h1p, (ushort_t*)0, (ushort_t*)0,
                       2400, 256, 3136, 448);
    hipLaunchKernelGGL(k_h1red, dim3(600), dim3(256), 0, stream, h1p, b1, h1H, h1L);
    // w2 (2400 x 512, K=256)   [W-resident]
    hipLaunchKernelGGL((k_wres<0, 0, 256, 64>), dim3(19 * 8), dim3(256), 0, stream,
                       h1H, h1L, w2TH, w2TL, b2, (float*)0, h2H, h2L, 2400, 512, 19);
    // w3 (2400 x 512, K=512)   [W-resident, NT=32]
    hipLaunchKernelGGL((k_wres<1, 0, 512, 32>), dim3(19 * 16), dim3(256), 0, stream,
                       h2H, h2L, w3TH, w3TL, b3, h3, (ushort_t*)0, (ushort_t*)0,
                       2400, 512, 19);
    // pts = tanh(h3 @ w4 + b4)  (hoisted from k_fuse)
    hipLaunchKernelGGL(k_pts, dim3(600), dim3(256), 0, stream, h3, w4, b4, pts);
    // fused sample + softmax-output (vectorized gather)
    hipLaunchKernelGGL(k_fuse, dim3(600), dim3(256), 0, stream,
                       roi, pts, gate, a2w, a2b, out);
}